// Round 7
// baseline (6163.631 us; speedup 1.0000x reference)
//
#include <hip/hip_runtime.h>
#include <cstdint>

#define BATCH 64
#define SEQ   1024
#define FEAT  16
#define HID   256
#define GATE  768    // 3*HID
#define TC    64     // time-chunk length
#define LASTC 15     // SEQ/TC - 1
#define NT    512    // fused-kernel block threads (8 waves)

typedef _Float16 f16x8 __attribute__((ext_vector_type(8)));
typedef float    f32x4 __attribute__((ext_vector_type(4)));

__device__ __forceinline__ float sigmoidf_(float x) { return 1.0f / (1.0f + __expf(-x)); }
__device__ __forceinline__ float tanhf_(float x)    { return 2.0f / (1.0f + __expf(-2.0f * x)) - 1.0f; }

// ---------------------------------------------------------------------------
// Pack U (fp32 [HID][GATE]) into MFMA B-fragments (f16).
// Fragment (ct, kt, lane): 8 f16 = U[kt*32 + (lane>>4)*8 + e][ct*16 + (lane&15)]
// at Bfrag[((ct*8 + kt)*64 + lane) * 4].
// ---------------------------------------------------------------------------
__global__ __launch_bounds__(256) void k_packB(const float* __restrict__ U,
                                               float* __restrict__ Bfrag)
{
    const int tid = blockIdx.x * 256 + threadIdx.x;   // < 48*8*64
    const int ct   = tid >> 9;
    const int kt   = (tid >> 6) & 7;
    const int lane = tid & 63;
    const int g = lane >> 4, i = lane & 15;
    const int col = ct * 16 + i;
    const int k0  = kt * 32 + g * 8;
    union { f16x8 v; float4 f; } u;
#pragma unroll
    for (int e = 0; e < 8; ++e)
        u.v[e] = (_Float16)U[(size_t)(k0 + e) * GATE + col];
    *(float4*)(Bfrag + (size_t)tid * 4) = u.f;
}

// ---------------------------------------------------------------------------
struct Params {
    const int*   batch;
    const float *W0, *b0, *W1, *b1, *W2, *b2;
    const float *Bf0, *Bf1, *Bf2;
    _Float16 *xp0a, *xp0b, *xp1a, *xp1b, *xp2a, *xp2b;  // f16 xp rings
    float *y0a, *y0b, *y1a, *y1b;                        // fp32 y rings
    float *h0, *h1, *h2;
    float *out, *hfin;
};

// ---------------------------------------------------------------------------
// GRU body, batch-in-M MFMA version. One block = 16 batch elements (b0..b0+15),
// all 256 h-cols, TC steps. 8 waves; wave w owns cols [32w,32w+32) x 3 gates.
// A = h[16 batch][K=256] (f16, LDS, A-fragment layout: addr=(kt*64+lane)*16B,
// linear -> conflict-free). B = U fragments, register/AGPR resident.
// C: lane(g=l>>4,i=l&15) reg r -> (batch 4g+r, col ct*16+i): every lane owns
// 8 real (batch,col) outputs; gates computed once, no duplication.
// ---------------------------------------------------------------------------
__device__ __forceinline__ void gru_body(
    char* smem, const _Float16* __restrict__ xp, const float* __restrict__ Bfrag,
    const float* __restrict__ bb, const int* __restrict__ batch,
    float* __restrict__ outp, int os, int obase,
    float* __restrict__ hfinal, float* __restrict__ hstate, int t0, int b0)
{
    _Float16* hA = (_Float16*)smem;                       // [2][4096] f16
    unsigned char* mk = (unsigned char*)(smem + 16384);   // [TC][16]

    const int T = threadIdx.x;
    const int w = T >> 6;
    const int l = T & 63;
    const int g = l >> 4;
    const int i = l & 15;

    // ---- register-resident B fragments: 6 col-tiles x 8 k-tiles ----
    // order: z(hf0), r(hf0), h(hf0), z(hf1), r(hf1), h(hf1)
    f16x8 Bf[6][8];
    {
        const int cts[6] = {2 * w, 16 + 2 * w, 32 + 2 * w,
                            2 * w + 1, 17 + 2 * w, 33 + 2 * w};
#pragma unroll
        for (int ci = 0; ci < 6; ++ci)
#pragma unroll
            for (int kt = 0; kt < 8; ++kt) {
                float4 v = *(const float4*)(Bfrag + ((size_t)(cts[ci] * 8 + kt) * 64 + l) * 4);
                Bf[ci][kt] = __builtin_bit_cast(f16x8, v);
            }
    }

    const float bh[2] = { bb[GATE + 2 * HID + 32 * w + i],
                          bb[GATE + 2 * HID + 32 * w + 16 + i] };

    // ---- stage mask for the whole chunk ----
    for (int idx = T; idx < TC * 16; idx += NT) {
        const int tl = idx >> 4, bt = idx & 15;
        mk[idx] = (batch[((size_t)(b0 + bt) * SEQ + t0 + tl) * FEAT + (FEAT - 1)] != -1);
    }

    // ---- init h (lane owns batch 4g+r, cols 32w+i / 32w+16+i) ----
    float hprev[2][4];
#pragma unroll
    for (int hf = 0; hf < 2; ++hf)
#pragma unroll
        for (int r = 0; r < 4; ++r) {
            const int bt = 4 * g + r, col = 32 * w + hf * 16 + i;
            float h0v = (t0 == 0) ? 0.0f : hstate[(size_t)(b0 + bt) * HID + col];
            hprev[hf][r] = h0v;
            hA[(w * 64 + (hf * 2 + (i >> 3)) * 16 + bt) * 8 + (i & 7)] = (_Float16)h0v;
        }
    __syncthreads();

    __builtin_amdgcn_s_setprio(1);

    for (int tl = 0; tl < TC; ++tl) {
        // xp loads (raw f16; converted after the mfma chain so latency hides)
        _Float16 xraw[3][2][4];
#pragma unroll
        for (int gt = 0; gt < 3; ++gt)
#pragma unroll
            for (int hf = 0; hf < 2; ++hf)
#pragma unroll
                for (int r = 0; r < 4; ++r)
                    xraw[gt][hf][r] = xp[((size_t)(b0 + 4 * g + r) * TC + tl) * GATE
                                         + gt * HID + 32 * w + hf * 16 + i];
        const unsigned m4 = *(const unsigned*)(mk + tl * 16 + 4 * g);

        const _Float16* rd = hA + (tl & 1) * 4096;
        _Float16*       wr = hA + ((tl & 1) ^ 1) * 4096;

        f32x4 acc[6];
#pragma unroll
        for (int ci = 0; ci < 6; ++ci) acc[ci] = (f32x4){0.f, 0.f, 0.f, 0.f};
#pragma unroll
        for (int kt = 0; kt < 8; ++kt) {
            const f16x8 a = *(const f16x8*)(rd + (kt * 64 + l) * 8);  // linear b128
            acc[0] = __builtin_amdgcn_mfma_f32_16x16x32_f16(a, Bf[0][kt], acc[0], 0, 0, 0);
            acc[1] = __builtin_amdgcn_mfma_f32_16x16x32_f16(a, Bf[1][kt], acc[1], 0, 0, 0);
            acc[2] = __builtin_amdgcn_mfma_f32_16x16x32_f16(a, Bf[2][kt], acc[2], 0, 0, 0);
            acc[3] = __builtin_amdgcn_mfma_f32_16x16x32_f16(a, Bf[3][kt], acc[3], 0, 0, 0);
            acc[4] = __builtin_amdgcn_mfma_f32_16x16x32_f16(a, Bf[4][kt], acc[4], 0, 0, 0);
            acc[5] = __builtin_amdgcn_mfma_f32_16x16x32_f16(a, Bf[5][kt], acc[5], 0, 0, 0);
        }

        // ---- gates: 8 real (batch,col) outputs per lane ----
#pragma unroll
        for (int hf = 0; hf < 2; ++hf) {
            const f32x4 az = acc[3 * hf + 0];
            const f32x4 ar = acc[3 * hf + 1];
            const f32x4 ah = acc[3 * hf + 2];
#pragma unroll
            for (int r = 0; r < 4; ++r) {
                const float xz = (float)xraw[0][hf][r];
                const float xr = (float)xraw[1][hf][r];
                const float xh = (float)xraw[2][hf][r];
                const float z  = sigmoidf_(xz + az[r]);
                const float rg = sigmoidf_(xr + ar[r]);
                const float hh = tanhf_(xh + rg * (ah[r] + bh[hf]));
                float hn = z * hprev[hf][r] + (1.0f - z) * hh;
                hn = ((m4 >> (8 * r)) & 0xff) ? hn : hprev[hf][r];
                hprev[hf][r] = hn;
                const int bt = 4 * g + r, col = 32 * w + hf * 16 + i;
                outp[((size_t)(b0 + bt) * os + obase + tl) * HID + col] = hn;
                wr[(w * 64 + (hf * 2 + (i >> 3)) * 16 + bt) * 8 + (i & 7)] = (_Float16)hn;
            }
        }
        // LDS-only barrier: skip the vmcnt(0) drain of xp loads / out stores
        asm volatile("s_waitcnt lgkmcnt(0)\n\ts_barrier" ::: "memory");
    }

    __builtin_amdgcn_s_setprio(0);

#pragma unroll
    for (int hf = 0; hf < 2; ++hf)
#pragma unroll
        for (int r = 0; r < 4; ++r) {
            const int bt = 4 * g + r, col = 32 * w + hf * 16 + i;
            hstate[(size_t)(b0 + bt) * HID + col] = hprev[hf][r];
            if (hfinal) hfinal[(size_t)(b0 + bt) * HID + col] = hprev[hf][r];
        }
}

// ---------------------------------------------------------------------------
// GEMM body (fp32, f16 output): xp[r,n] = bias(n) + sum_k Yc[r,k]*W[k,n]
// 512 threads, 64x128 tile, BK=16, 4x4 micro-tile. e: bx=e/6, by=e%6.
// ---------------------------------------------------------------------------
__device__ __forceinline__ void gemm_body(
    char* smem, const float* __restrict__ Yc, const float* __restrict__ W,
    const float* __restrict__ bb, _Float16* __restrict__ xpout, int e)
{
    float (*As)[68]  = (float (*)[68])smem;                    // [16][68]
    float (*Bs)[128] = (float (*)[128])(smem + 16 * 68 * 4);   // [16][128]

    const int bx = e / 6, by = e % 6;
    const int m0 = bx * 64, n0 = by * 128;
    const int tid = threadIdx.x;
    const int lrA = tid >> 3, lcA = (tid & 7) * 2;
    const int lrB = tid >> 5, lcB = (tid & 31) * 4;
    const int ty = tid >> 5, tx = tid & 31;

    float acc[4][4] = {};

    for (int k0 = 0; k0 < HID; k0 += 16) {
        float2 av = *(const float2*)(Yc + (size_t)(m0 + lrA) * HID + k0 + lcA);
        As[lcA][lrA] = av.x; As[lcA + 1][lrA] = av.y;
        float4 bv = *(const float4*)(W + (size_t)(k0 + lrB) * GATE + n0 + lcB);
        *(float4*)&Bs[lrB][lcB] = bv;
        __syncthreads();
#pragma unroll
        for (int k = 0; k < 16; ++k) {
            float4 a  = *(const float4*)&As[k][ty * 4];
            float4 bq = *(const float4*)&Bs[k][tx * 4];
            float a_[4] = {a.x, a.y, a.z, a.w};
            float b_[4] = {bq.x, bq.y, bq.z, bq.w};
#pragma unroll
            for (int ii = 0; ii < 4; ++ii)
#pragma unroll
                for (int jj = 0; jj < 4; ++jj)
                    acc[ii][jj] += a_[ii] * b_[jj];
        }
        __syncthreads();
    }

#pragma unroll
    for (int ii = 0; ii < 4; ++ii) {
        const int row = m0 + ty * 4 + ii;
        union { _Float16 h[4]; float2 f2; } u;
#pragma unroll
        for (int jj = 0; jj < 4; ++jj) {
            const int n = n0 + tx * 4 + jj;
            u.h[jj] = (_Float16)(acc[ii][jj] + bb[n] + ((n < 2 * HID) ? bb[GATE + n] : 0.0f));
        }
        *(float2*)&xpout[(size_t)row * GATE + n0 + tx * 4] = u.f2;
    }
}

// ---------------------------------------------------------------------------
// Layer-0 projection body (f16 output): one block per batch element.
// ---------------------------------------------------------------------------
__device__ __forceinline__ void xp0_body(
    const int* __restrict__ batch, const float* __restrict__ W0,
    const float* __restrict__ bb, _Float16* __restrict__ xpout, int t0, int b)
{
    const int tid = threadIdx.x;
    for (int tl = 0; tl < TC; ++tl) {
        const int* xr = batch + ((size_t)b * SEQ + t0 + tl) * FEAT;
        float xf[FEAT];
#pragma unroll
        for (int f = 0; f < FEAT; ++f) xf[f] = (float)xr[f];
        for (int cc = tid; cc < GATE; cc += NT) {
            float acc = bb[cc] + ((cc < 2 * HID) ? bb[GATE + cc] : 0.0f);
#pragma unroll
            for (int f = 0; f < FEAT; ++f)
                acc += xf[f] * W0[f * GATE + cc];
            xpout[((size_t)b * TC + tl) * GATE + cc] = (_Float16)acc;
        }
    }
}

// ---------------------------------------------------------------------------
// Fused pipeline kernel. Launch d:
//   bid   0-  3 : gru layer0, chunk d      (b0 = bid*16)
//   bid   4-  7 : gru layer1, chunk d-2
//   bid   8- 11 : gru layer2, chunk d-4
//   bid  12- 75 : xp0 projection, chunk d+1
//   bid  76-459 : gemm layer1 xp, chunk d-1
//   bid 460-843 : gemm layer2 xp, chunk d-3
// ---------------------------------------------------------------------------
__global__ __launch_bounds__(NT, 1) void k_fused(Params P, int d)
{
    __shared__ __align__(16) char smem[17408];
    const int bid = blockIdx.x;

    if (bid < 4) {
        const int c = d;
        if (c >= 0 && c <= LASTC)
            gru_body(smem, (c & 1) ? P.xp0b : P.xp0a, P.Bf0, P.b0, P.batch,
                     (c & 1) ? P.y0b : P.y0a, TC, 0, nullptr, P.h0, c * TC, bid * 16);
    } else if (bid < 8) {
        const int c = d - 2;
        if (c >= 0 && c <= LASTC)
            gru_body(smem, (c & 1) ? P.xp1b : P.xp1a, P.Bf1, P.b1, P.batch,
                     (c & 1) ? P.y1b : P.y1a, TC, 0, nullptr, P.h1, c * TC, (bid - 4) * 16);
    } else if (bid < 12) {
        const int c = d - 4;
        if (c >= 0 && c <= LASTC)
            gru_body(smem, (c & 1) ? P.xp2b : P.xp2a, P.Bf2, P.b2, P.batch,
                     P.out, SEQ, c * TC, (c == LASTC) ? P.hfin : nullptr,
                     P.h2, c * TC, (bid - 8) * 16);
    } else if (bid < 76) {
        const int c = d + 1;
        if (c >= 0 && c <= LASTC)
            xp0_body(P.batch, P.W0, P.b0, (c & 1) ? P.xp0b : P.xp0a, c * TC, bid - 12);
    } else if (bid < 460) {
        const int c = d - 1;
        if (c >= 0 && c <= LASTC)
            gemm_body(smem, (c & 1) ? P.y0b : P.y0a, P.W1, P.b1,
                      (c & 1) ? P.xp1b : P.xp1a, bid - 76);
    } else {
        const int c = d - 3;
        if (c >= 0 && c <= LASTC)
            gemm_body(smem, (c & 1) ? P.y1b : P.y1a, P.W2, P.b2,
                      (c & 1) ? P.xp2b : P.xp2a, bid - 460);
    }
}

// ---------------------------------------------------------------------------
extern "C" void kernel_launch(void* const* d_in, const int* in_sizes, int n_in,
                              void* d_out, int out_size, void* d_ws, size_t ws_size,
                              hipStream_t stream)
{
    const int*   batch = (const int*)d_in[0];
    const float* W0 = (const float*)d_in[1];
    const float* U0 = (const float*)d_in[2];
    const float* b0 = (const float*)d_in[3];
    const float* W1 = (const float*)d_in[4];
    const float* U1 = (const float*)d_in[5];
    const float* b1 = (const float*)d_in[6];
    const float* W2 = (const float*)d_in[7];
    const float* U2 = (const float*)d_in[8];
    const float* b2 = (const float*)d_in[9];

    float* out  = (float*)d_out;
    float* hfin = out + (size_t)BATCH * SEQ * HID;

    const size_t XPB = (size_t)BATCH * TC * GATE * 2;   // f16 xp chunk bytes
    const size_t YB  = (size_t)BATCH * TC * HID * 4;    // fp32 y chunk bytes
    const size_t HB  = (size_t)BATCH * HID * 4;
    const size_t BFB = (size_t)48 * 8 * 64 * 4 * 4;     // B-frag bytes

    char* p = (char*)d_ws;
    auto alloc = [&](size_t bytes) { char* q = p; p += (bytes + 255) & ~(size_t)255; return q; };
    _Float16* xp0a = (_Float16*)alloc(XPB);
    _Float16* xp0b = (_Float16*)alloc(XPB);
    _Float16* xp1a = (_Float16*)alloc(XPB);
    _Float16* xp1b = (_Float16*)alloc(XPB);
    _Float16* xp2a = (_Float16*)alloc(XPB);
    _Float16* xp2b = (_Float16*)alloc(XPB);
    float* y0a = (float*)alloc(YB);
    float* y0b = (float*)alloc(YB);
    float* y1a = (float*)alloc(YB);
    float* y1b = (float*)alloc(YB);
    float* h0  = (float*)alloc(HB);
    float* h1  = (float*)alloc(HB);
    float* h2  = (float*)alloc(HB);
    float* Bf0 = (float*)alloc(BFB);
    float* Bf1 = (float*)alloc(BFB);
    float* Bf2 = (float*)alloc(BFB);

    dim3 gpack(48 * 8 * 64 / 256), bpack(256);
    k_packB<<<gpack, bpack, 0, stream>>>(U0, Bf0);
    k_packB<<<gpack, bpack, 0, stream>>>(U1, Bf1);
    k_packB<<<gpack, bpack, 0, stream>>>(U2, Bf2);

    Params P;
    P.batch = batch;
    P.W0 = W0; P.b0 = b0; P.W1 = W1; P.b1 = b1; P.W2 = W2; P.b2 = b2;
    P.Bf0 = Bf0; P.Bf1 = Bf1; P.Bf2 = Bf2;
    P.xp0a = xp0a; P.xp0b = xp0b; P.xp1a = xp1a; P.xp1b = xp1b;
    P.xp2a = xp2a; P.xp2b = xp2b;
    P.y0a = y0a; P.y0b = y0b; P.y1a = y1a; P.y1b = y1b;
    P.h0 = h0; P.h1 = h1; P.h2 = h2;
    P.out = out; P.hfin = hfin;

    for (int d = -1; d <= LASTC + 4; ++d)
        k_fused<<<dim3(844), dim3(NT), 0, stream>>>(P, d);
}

// Round 8
// 4609.176 us; speedup vs baseline: 1.3373x; 1.3373x over previous
//
#include <hip/hip_runtime.h>
#include <cstdint>

#define BATCH 64
#define SEQ   1024
#define FEAT  16
#define HID   256
#define GATE  768    // 3*HID
#define TC    64     // time-chunk length
#define LASTC 15     // SEQ/TC - 1
#define NT    512    // fused-kernel block threads (8 waves)
#define GB    4      // batches per GRU block
#define NGRU  16     // GRU blocks per layer (BATCH/GB)

typedef _Float16 f16x8 __attribute__((ext_vector_type(8)));
typedef float    f32x4 __attribute__((ext_vector_type(4)));

__device__ __forceinline__ float sigmoidf_(float x) { return 1.0f / (1.0f + __expf(-x)); }
__device__ __forceinline__ float tanhf_(float x)    { return 2.0f / (1.0f + __expf(-2.0f * x)) - 1.0f; }

// ---------------------------------------------------------------------------
// Pack U (fp32 [HID][GATE]) into MFMA B-fragments (f16).
// Fragment (ct, kt, lane): 8 f16 = U[kt*32 + (lane>>4)*8 + e][ct*16 + (lane&15)]
// at Bfrag[((ct*8 + kt)*64 + lane) * 4].
// ---------------------------------------------------------------------------
__global__ __launch_bounds__(256) void k_packB(const float* __restrict__ U,
                                               float* __restrict__ Bfrag)
{
    const int tid = blockIdx.x * 256 + threadIdx.x;   // < 48*8*64
    const int ct   = tid >> 9;
    const int kt   = (tid >> 6) & 7;
    const int lane = tid & 63;
    const int g = lane >> 4, i = lane & 15;
    const int col = ct * 16 + i;
    const int k0  = kt * 32 + g * 8;
    union { f16x8 v; float4 f; } u;
#pragma unroll
    for (int e = 0; e < 8; ++e)
        u.v[e] = (_Float16)U[(size_t)(k0 + e) * GATE + col];
    *(float4*)(Bfrag + (size_t)tid * 4) = u.f;
}

// ---------------------------------------------------------------------------
struct Params {
    const int*   batch;
    const float *W0, *b0, *W1, *b1, *W2, *b2;
    const float *Bf0, *Bf1, *Bf2;
    _Float16 *xp0a, *xp0b, *xp1a, *xp1b, *xp2a, *xp2b;  // f16 xp rings
    float *y0a, *y0b, *y1a, *y1b;                        // fp32 y rings
    float *h0, *h1, *h2;
    float *out, *hfin;
};

// ---------------------------------------------------------------------------
// GRU body, batch-in-M MFMA, 4 batches/block (4x replicated in M).
// A rows: row&3 = batch; C: lane(g=l>>4,i=l&15) reg r -> (batch r, col
// ct*16+i), identical across g (replicas). hA slot bt=4g+r holds replica g
// of batch r -> LDS/mfma code identical to the verified 16-batch version.
// Global accesses use b0+r; out/hstate stores gated g==0.
// xp loads hf-split (12 live regs, not 24) to stay under the spill cliff.
// ---------------------------------------------------------------------------
__device__ __forceinline__ void gru_body(
    char* smem, const _Float16* __restrict__ xp, const float* __restrict__ Bfrag,
    const float* __restrict__ bb, const int* __restrict__ batch,
    float* __restrict__ outp, int os, int obase,
    float* __restrict__ hfinal, float* __restrict__ hstate, int t0, int b0)
{
    _Float16* hA = (_Float16*)smem;                       // [2][4096] f16
    unsigned char* mk = (unsigned char*)(smem + 16384);   // [TC][4]

    const int T = threadIdx.x;
    const int w = T >> 6;
    const int l = T & 63;
    const int g = l >> 4;
    const int i = l & 15;

    // ---- register-resident B fragments: 6 col-tiles x 8 k-tiles ----
    f16x8 Bf[6][8];
    {
        const int cts[6] = {2 * w, 16 + 2 * w, 32 + 2 * w,
                            2 * w + 1, 17 + 2 * w, 33 + 2 * w};
#pragma unroll
        for (int ci = 0; ci < 6; ++ci)
#pragma unroll
            for (int kt = 0; kt < 8; ++kt) {
                float4 v = *(const float4*)(Bfrag + ((size_t)(cts[ci] * 8 + kt) * 64 + l) * 4);
                Bf[ci][kt] = __builtin_bit_cast(f16x8, v);
            }
    }

    const float bh[2] = { bb[GATE + 2 * HID + 32 * w + i],
                          bb[GATE + 2 * HID + 32 * w + 16 + i] };

    // ---- stage mask for the whole chunk: mk[tl][r], r=0..3 ----
    for (int idx = T; idx < TC * GB; idx += NT) {
        const int tl = idx >> 2, r = idx & 3;
        mk[idx] = (batch[((size_t)(b0 + r) * SEQ + t0 + tl) * FEAT + (FEAT - 1)] != -1);
    }

    // ---- init h: lane owns (batch r, cols 32w+i / 32w+16+i), replica g ----
    float hprev[2][4];
#pragma unroll
    for (int hf = 0; hf < 2; ++hf)
#pragma unroll
        for (int r = 0; r < 4; ++r) {
            const int bt = 4 * g + r, col = 32 * w + hf * 16 + i;
            float h0v = (t0 == 0) ? 0.0f : hstate[(size_t)(b0 + r) * HID + col];
            hprev[hf][r] = h0v;
            hA[(w * 64 + (hf * 2 + (i >> 3)) * 16 + bt) * 8 + (i & 7)] = (_Float16)h0v;
        }
    __syncthreads();

    __builtin_amdgcn_s_setprio(1);

    for (int tl = 0; tl < TC; ++tl) {
        // hf0 xp loads (12 ushort; consumed after the mfma chain)
        _Float16 x0[3][4];
#pragma unroll
        for (int gt = 0; gt < 3; ++gt)
#pragma unroll
            for (int r = 0; r < 4; ++r)
                x0[gt][r] = xp[((size_t)(b0 + r) * TC + tl) * GATE
                               + gt * HID + 32 * w + i];
        const unsigned m4 = *(const unsigned*)(mk + tl * 4);

        const _Float16* rd = hA + (tl & 1) * 4096;
        _Float16*       wr = hA + ((tl & 1) ^ 1) * 4096;

        f32x4 acc[6];
#pragma unroll
        for (int ci = 0; ci < 6; ++ci) acc[ci] = (f32x4){0.f, 0.f, 0.f, 0.f};
#pragma unroll
        for (int kt = 0; kt < 8; ++kt) {
            const f16x8 a = *(const f16x8*)(rd + (kt * 64 + l) * 8);  // linear b128
            acc[0] = __builtin_amdgcn_mfma_f32_16x16x32_f16(a, Bf[0][kt], acc[0], 0, 0, 0);
            acc[1] = __builtin_amdgcn_mfma_f32_16x16x32_f16(a, Bf[1][kt], acc[1], 0, 0, 0);
            acc[2] = __builtin_amdgcn_mfma_f32_16x16x32_f16(a, Bf[2][kt], acc[2], 0, 0, 0);
            acc[3] = __builtin_amdgcn_mfma_f32_16x16x32_f16(a, Bf[3][kt], acc[3], 0, 0, 0);
            acc[4] = __builtin_amdgcn_mfma_f32_16x16x32_f16(a, Bf[4][kt], acc[4], 0, 0, 0);
            acc[5] = __builtin_amdgcn_mfma_f32_16x16x32_f16(a, Bf[5][kt], acc[5], 0, 0, 0);
        }

        // hf1 xp loads (issued now, consumed after hf0 gates -> latency hidden)
        _Float16 x1[3][4];
#pragma unroll
        for (int gt = 0; gt < 3; ++gt)
#pragma unroll
            for (int r = 0; r < 4; ++r)
                x1[gt][r] = xp[((size_t)(b0 + r) * TC + tl) * GATE
                               + gt * HID + 32 * w + 16 + i];

        // ---- gates hf0 (cols 32w+i) ----
#pragma unroll
        for (int r = 0; r < 4; ++r) {
            const float z  = sigmoidf_((float)x0[0][r] + acc[0][r]);
            const float rg = sigmoidf_((float)x0[1][r] + acc[1][r]);
            const float hh = tanhf_((float)x0[2][r] + rg * (acc[2][r] + bh[0]));
            float hn = z * hprev[0][r] + (1.0f - z) * hh;
            hn = ((m4 >> (8 * r)) & 0xff) ? hn : hprev[0][r];
            hprev[0][r] = hn;
            const int bt = 4 * g + r, col = 32 * w + i;
            if (g == 0)
                outp[((size_t)(b0 + r) * os + obase + tl) * HID + col] = hn;
            wr[(w * 64 + (i >> 3) * 16 + bt) * 8 + (i & 7)] = (_Float16)hn;
        }
        // ---- gates hf1 (cols 32w+16+i) ----
#pragma unroll
        for (int r = 0; r < 4; ++r) {
            const float z  = sigmoidf_((float)x1[0][r] + acc[3][r]);
            const float rg = sigmoidf_((float)x1[1][r] + acc[4][r]);
            const float hh = tanhf_((float)x1[2][r] + rg * (acc[5][r] + bh[1]));
            float hn = z * hprev[1][r] + (1.0f - z) * hh;
            hn = ((m4 >> (8 * r)) & 0xff) ? hn : hprev[1][r];
            hprev[1][r] = hn;
            const int bt = 4 * g + r, col = 32 * w + 16 + i;
            if (g == 0)
                outp[((size_t)(b0 + r) * os + obase + tl) * HID + col] = hn;
            wr[(w * 64 + (2 + (i >> 3)) * 16 + bt) * 8 + (i & 7)] = (_Float16)hn;
        }
        // LDS-only barrier: skip vmcnt(0) drain of xp loads / out stores
        asm volatile("s_waitcnt lgkmcnt(0)\n\ts_barrier" ::: "memory");
    }

    __builtin_amdgcn_s_setprio(0);

    if (g == 0) {
#pragma unroll
        for (int hf = 0; hf < 2; ++hf)
#pragma unroll
            for (int r = 0; r < 4; ++r) {
                const int col = 32 * w + hf * 16 + i;
                hstate[(size_t)(b0 + r) * HID + col] = hprev[hf][r];
                if (hfinal) hfinal[(size_t)(b0 + r) * HID + col] = hprev[hf][r];
            }
    }
}

// ---------------------------------------------------------------------------
// GEMM body (fp32, f16 output): xp[r,n] = bias(n) + sum_k Yc[r,k]*W[k,n]
// 512 threads, 64x128 tile, BK=16, 4x4 micro-tile. e: bx=e/6, by=e%6.
// ---------------------------------------------------------------------------
__device__ __forceinline__ void gemm_body(
    char* smem, const float* __restrict__ Yc, const float* __restrict__ W,
    const float* __restrict__ bb, _Float16* __restrict__ xpout, int e)
{
    float (*As)[68]  = (float (*)[68])smem;                    // [16][68]
    float (*Bs)[128] = (float (*)[128])(smem + 16 * 68 * 4);   // [16][128]

    const int bx = e / 6, by = e % 6;
    const int m0 = bx * 64, n0 = by * 128;
    const int tid = threadIdx.x;
    const int lrA = tid >> 3, lcA = (tid & 7) * 2;
    const int lrB = tid >> 5, lcB = (tid & 31) * 4;
    const int ty = tid >> 5, tx = tid & 31;

    float acc[4][4] = {};

    for (int k0 = 0; k0 < HID; k0 += 16) {
        float2 av = *(const float2*)(Yc + (size_t)(m0 + lrA) * HID + k0 + lcA);
        As[lcA][lrA] = av.x; As[lcA + 1][lrA] = av.y;
        float4 bv = *(const float4*)(W + (size_t)(k0 + lrB) * GATE + n0 + lcB);
        *(float4*)&Bs[lrB][lcB] = bv;
        __syncthreads();
#pragma unroll
        for (int k = 0; k < 16; ++k) {
            float4 a  = *(const float4*)&As[k][ty * 4];
            float4 bq = *(const float4*)&Bs[k][tx * 4];
            float a_[4] = {a.x, a.y, a.z, a.w};
            float b_[4] = {bq.x, bq.y, bq.z, bq.w};
#pragma unroll
            for (int ii = 0; ii < 4; ++ii)
#pragma unroll
                for (int jj = 0; jj < 4; ++jj)
                    acc[ii][jj] += a_[ii] * b_[jj];
        }
        __syncthreads();
    }

#pragma unroll
    for (int ii = 0; ii < 4; ++ii) {
        const int row = m0 + ty * 4 + ii;
        union { _Float16 h[4]; float2 f2; } u;
#pragma unroll
        for (int jj = 0; jj < 4; ++jj) {
            const int n = n0 + tx * 4 + jj;
            u.h[jj] = (_Float16)(acc[ii][jj] + bb[n] + ((n < 2 * HID) ? bb[GATE + n] : 0.0f));
        }
        *(float2*)&xpout[(size_t)row * GATE + n0 + tx * 4] = u.f2;
    }
}

// ---------------------------------------------------------------------------
// Layer-0 projection body (f16 output): one block per batch element.
// ---------------------------------------------------------------------------
__device__ __forceinline__ void xp0_body(
    const int* __restrict__ batch, const float* __restrict__ W0,
    const float* __restrict__ bb, _Float16* __restrict__ xpout, int t0, int b)
{
    const int tid = threadIdx.x;
    for (int tl = 0; tl < TC; ++tl) {
        const int* xr = batch + ((size_t)b * SEQ + t0 + tl) * FEAT;
        float xf[FEAT];
#pragma unroll
        for (int f = 0; f < FEAT; ++f) xf[f] = (float)xr[f];
        for (int cc = tid; cc < GATE; cc += NT) {
            float acc = bb[cc] + ((cc < 2 * HID) ? bb[GATE + cc] : 0.0f);
#pragma unroll
            for (int f = 0; f < FEAT; ++f)
                acc += xf[f] * W0[f * GATE + cc];
            xpout[((size_t)b * TC + tl) * GATE + cc] = (_Float16)acc;
        }
    }
}

// ---------------------------------------------------------------------------
// Fused pipeline kernel. Launch d:
//   bid   0- 15 : gru layer0, chunk d      (b0 = bid*4)
//   bid  16- 31 : gru layer1, chunk d-2
//   bid  32- 47 : gru layer2, chunk d-4
//   bid  48-111 : xp0 projection, chunk d+1
//   bid 112-495 : gemm layer1 xp, chunk d-1
//   bid 496-879 : gemm layer2 xp, chunk d-3
// ---------------------------------------------------------------------------
__global__ __launch_bounds__(NT, 1) void k_fused(Params P, int d)
{
    __shared__ __align__(16) char smem[17408];
    const int bid = blockIdx.x;

    if (bid < NGRU) {
        const int c = d;
        if (c >= 0 && c <= LASTC)
            gru_body(smem, (c & 1) ? P.xp0b : P.xp0a, P.Bf0, P.b0, P.batch,
                     (c & 1) ? P.y0b : P.y0a, TC, 0, nullptr, P.h0, c * TC, bid * GB);
    } else if (bid < 2 * NGRU) {
        const int c = d - 2;
        if (c >= 0 && c <= LASTC)
            gru_body(smem, (c & 1) ? P.xp1b : P.xp1a, P.Bf1, P.b1, P.batch,
                     (c & 1) ? P.y1b : P.y1a, TC, 0, nullptr, P.h1, c * TC, (bid - NGRU) * GB);
    } else if (bid < 3 * NGRU) {
        const int c = d - 4;
        if (c >= 0 && c <= LASTC)
            gru_body(smem, (c & 1) ? P.xp2b : P.xp2a, P.Bf2, P.b2, P.batch,
                     P.out, SEQ, c * TC, (c == LASTC) ? P.hfin : nullptr,
                     P.h2, c * TC, (bid - 2 * NGRU) * GB);
    } else if (bid < 3 * NGRU + 64) {
        const int c = d + 1;
        if (c >= 0 && c <= LASTC)
            xp0_body(P.batch, P.W0, P.b0, (c & 1) ? P.xp0b : P.xp0a,
                     c * TC, bid - 3 * NGRU);
    } else if (bid < 3 * NGRU + 64 + 384) {
        const int c = d - 1;
        if (c >= 0 && c <= LASTC)
            gemm_body(smem, (c & 1) ? P.y0b : P.y0a, P.W1, P.b1,
                      (c & 1) ? P.xp1b : P.xp1a, bid - (3 * NGRU + 64));
    } else {
        const int c = d - 3;
        if (c >= 0 && c <= LASTC)
            gemm_body(smem, (c & 1) ? P.y1b : P.y1a, P.W2, P.b2,
                      (c & 1) ? P.xp2b : P.xp2a, bid - (3 * NGRU + 64 + 384));
    }
}

// ---------------------------------------------------------------------------
extern "C" void kernel_launch(void* const* d_in, const int* in_sizes, int n_in,
                              void* d_out, int out_size, void* d_ws, size_t ws_size,
                              hipStream_t stream)
{
    const int*   batch = (const int*)d_in[0];
    const float* W0 = (const float*)d_in[1];
    const float* U0 = (const float*)d_in[2];
    const float* b0 = (const float*)d_in[3];
    const float* W1 = (const float*)d_in[4];
    const float* U1 = (const float*)d_in[5];
    const float* b1 = (const float*)d_in[6];
    const float* W2 = (const float*)d_in[7];
    const float* U2 = (const float*)d_in[8];
    const float* b2 = (const float*)d_in[9];

    float* out  = (float*)d_out;
    float* hfin = out + (size_t)BATCH * SEQ * HID;

    const size_t XPB = (size_t)BATCH * TC * GATE * 2;   // f16 xp chunk bytes
    const size_t YB  = (size_t)BATCH * TC * HID * 4;    // fp32 y chunk bytes
    const size_t HB  = (size_t)BATCH * HID * 4;
    const size_t BFB = (size_t)48 * 8 * 64 * 4 * 4;     // B-frag bytes

    char* p = (char*)d_ws;
    auto alloc = [&](size_t bytes) { char* q = p; p += (bytes + 255) & ~(size_t)255; return q; };
    _Float16* xp0a = (_Float16*)alloc(XPB);
    _Float16* xp0b = (_Float16*)alloc(XPB);
    _Float16* xp1a = (_Float16*)alloc(XPB);
    _Float16* xp1b = (_Float16*)alloc(XPB);
    _Float16* xp2a = (_Float16*)alloc(XPB);
    _Float16* xp2b = (_Float16*)alloc(XPB);
    float* y0a = (float*)alloc(YB);
    float* y0b = (float*)alloc(YB);
    float* y1a = (float*)alloc(YB);
    float* y1b = (float*)alloc(YB);
    float* h0  = (float*)alloc(HB);
    float* h1  = (float*)alloc(HB);
    float* h2  = (float*)alloc(HB);
    float* Bf0 = (float*)alloc(BFB);
    float* Bf1 = (float*)alloc(BFB);
    float* Bf2 = (float*)alloc(BFB);

    dim3 gpack(48 * 8 * 64 / 256), bpack(256);
    k_packB<<<gpack, bpack, 0, stream>>>(U0, Bf0);
    k_packB<<<gpack, bpack, 0, stream>>>(U1, Bf1);
    k_packB<<<gpack, bpack, 0, stream>>>(U2, Bf2);

    Params P;
    P.batch = batch;
    P.W0 = W0; P.b0 = b0; P.W1 = W1; P.b1 = b1; P.W2 = W2; P.b2 = b2;
    P.Bf0 = Bf0; P.Bf1 = Bf1; P.Bf2 = Bf2;
    P.xp0a = xp0a; P.xp0b = xp0b; P.xp1a = xp1a; P.xp1b = xp1b;
    P.xp2a = xp2a; P.xp2b = xp2b;
    P.y0a = y0a; P.y0b = y0b; P.y1a = y1a; P.y1b = y1b;
    P.h0 = h0; P.h1 = h1; P.h2 = h2;
    P.out = out; P.hfin = hfin;

    for (int d = -1; d <= LASTC + 4; ++d)
        k_fused<<<dim3(880), dim3(NT), 0, stream>>>(P, d);
}

// Round 9
// 4599.678 us; speedup vs baseline: 1.3400x; 1.0021x over previous
//
#include <hip/hip_runtime.h>
#include <cstdint>

#define BATCH 64
#define SEQ   1024
#define FEAT  16
#define HID   256
#define GATE  768    // 3*HID
#define TC    64     // time-chunk length
#define LASTC 15     // SEQ/TC - 1
#define NT    512    // block threads (8 waves)
#define GB    4      // batches per GRU block
#define NGRU  16     // GRU blocks per layer (BATCH/GB)
#define NWRK  208    // worker blocks (256 - 48)
#define NITEM 832    // 64 xp0 + 384 gemm1 + 384 gemm2

typedef _Float16 f16x8 __attribute__((ext_vector_type(8)));
typedef float    f32x4 __attribute__((ext_vector_type(4)));

__device__ __forceinline__ float sigmoidf_(float x) { return 1.0f / (1.0f + __expf(-x)); }
__device__ __forceinline__ float tanhf_(float x)    { return 2.0f / (1.0f + __expf(-2.0f * x)) - 1.0f; }

// ---------------------------------------------------------------------------
// Pack U (fp32 [HID][GATE]) into MFMA B-fragments (f16).
// Fragment (ct, kt, lane): 8 f16 = U[kt*32 + (lane>>4)*8 + e][ct*16 + (lane&15)]
// at Bfrag[((ct*8 + kt)*64 + lane) * 4].
// ---------------------------------------------------------------------------
__global__ __launch_bounds__(256) void k_packB(const float* __restrict__ U,
                                               float* __restrict__ Bfrag)
{
    const int tid = blockIdx.x * 256 + threadIdx.x;   // < 48*8*64
    const int ct   = tid >> 9;
    const int kt   = (tid >> 6) & 7;
    const int lane = tid & 63;
    const int g = lane >> 4, i = lane & 15;
    const int col = ct * 16 + i;
    const int k0  = kt * 32 + g * 8;
    union { f16x8 v; float4 f; } u;
#pragma unroll
    for (int e = 0; e < 8; ++e)
        u.v[e] = (_Float16)U[(size_t)(k0 + e) * GATE + col];
    *(float4*)(Bfrag + (size_t)tid * 4) = u.f;
}

// ---------------------------------------------------------------------------
struct Params {
    const int*   batch;
    const float *W0, *b0, *W1, *b1, *W2, *b2;
    const float *Bf0, *Bf1, *Bf2;
    _Float16 *xp0a, *xp0b, *xp1a, *xp1b, *xp2a, *xp2b;  // f16 xp rings
    float *y0a, *y0b, *y1a, *y1b;                        // fp32 y rings
    float *h0, *h1, *h2;
    float *out, *hfin;
};

// ---------------------------------------------------------------------------
// GRU body, batch-in-M MFMA, 4 batches/block (4x replicated in M).
// A rows: row&3 = batch; C: lane(g=l>>4,i=l&15) reg r -> (batch r, col
// ct*16+i), identical across g (replicas). All 24 xp loads hoisted before
// the mfma chain (full chain hides L2 latency). Stores gated g==0.
// ---------------------------------------------------------------------------
__device__ __forceinline__ void gru_body(
    char* smem, const _Float16* __restrict__ xp, const float* __restrict__ Bfrag,
    const float* __restrict__ bb, const int* __restrict__ batch,
    float* __restrict__ outp, int os, int obase,
    float* __restrict__ hfinal, float* __restrict__ hstate, int t0, int b0)
{
    _Float16* hA = (_Float16*)smem;                       // [2][4096] f16
    unsigned char* mk = (unsigned char*)(smem + 16384);   // [TC][4]

    const int T = threadIdx.x;
    const int w = T >> 6;
    const int l = T & 63;
    const int g = l >> 4;
    const int i = l & 15;

    // ---- register-resident B fragments: 6 col-tiles x 8 k-tiles ----
    f16x8 Bf[6][8];
    {
        const int cts[6] = {2 * w, 16 + 2 * w, 32 + 2 * w,
                            2 * w + 1, 17 + 2 * w, 33 + 2 * w};
#pragma unroll
        for (int ci = 0; ci < 6; ++ci)
#pragma unroll
            for (int kt = 0; kt < 8; ++kt) {
                float4 v = *(const float4*)(Bfrag + ((size_t)(cts[ci] * 8 + kt) * 64 + l) * 4);
                Bf[ci][kt] = __builtin_bit_cast(f16x8, v);
            }
    }

    const float bh[2] = { bb[GATE + 2 * HID + 32 * w + i],
                          bb[GATE + 2 * HID + 32 * w + 16 + i] };

    // ---- stage mask for the whole chunk: mk[tl][r], r=0..3 ----
    for (int idx = T; idx < TC * GB; idx += NT) {
        const int tl = idx >> 2, r = idx & 3;
        mk[idx] = (batch[((size_t)(b0 + r) * SEQ + t0 + tl) * FEAT + (FEAT - 1)] != -1);
    }

    // ---- init h: lane owns (batch r, cols 32w+i / 32w+16+i), replica g ----
    float hprev[2][4];
#pragma unroll
    for (int hf = 0; hf < 2; ++hf)
#pragma unroll
        for (int r = 0; r < 4; ++r) {
            const int bt = 4 * g + r, col = 32 * w + hf * 16 + i;
            float h0v = (t0 == 0) ? 0.0f : hstate[(size_t)(b0 + r) * HID + col];
            hprev[hf][r] = h0v;
            hA[(w * 64 + (hf * 2 + (i >> 3)) * 16 + bt) * 8 + (i & 7)] = (_Float16)h0v;
        }
    __syncthreads();

    __builtin_amdgcn_s_setprio(1);

    for (int tl = 0; tl < TC; ++tl) {
        // all 24 xp loads issued before the mfma chain (latency hidden under it)
        _Float16 x0[3][4], x1[3][4];
#pragma unroll
        for (int gt = 0; gt < 3; ++gt)
#pragma unroll
            for (int r = 0; r < 4; ++r) {
                const _Float16* base = xp + ((size_t)(b0 + r) * TC + tl) * GATE
                                          + gt * HID + 32 * w + i;
                x0[gt][r] = base[0];
                x1[gt][r] = base[16];
            }
        const unsigned m4 = *(const unsigned*)(mk + tl * 4);

        const _Float16* rd = hA + (tl & 1) * 4096;
        _Float16*       wr = hA + ((tl & 1) ^ 1) * 4096;

        f32x4 acc[6];
#pragma unroll
        for (int ci = 0; ci < 6; ++ci) acc[ci] = (f32x4){0.f, 0.f, 0.f, 0.f};
#pragma unroll
        for (int kt = 0; kt < 8; ++kt) {
            const f16x8 a = *(const f16x8*)(rd + (kt * 64 + l) * 8);  // linear b128
            acc[0] = __builtin_amdgcn_mfma_f32_16x16x32_f16(a, Bf[0][kt], acc[0], 0, 0, 0);
            acc[1] = __builtin_amdgcn_mfma_f32_16x16x32_f16(a, Bf[1][kt], acc[1], 0, 0, 0);
            acc[2] = __builtin_amdgcn_mfma_f32_16x16x32_f16(a, Bf[2][kt], acc[2], 0, 0, 0);
            acc[3] = __builtin_amdgcn_mfma_f32_16x16x32_f16(a, Bf[3][kt], acc[3], 0, 0, 0);
            acc[4] = __builtin_amdgcn_mfma_f32_16x16x32_f16(a, Bf[4][kt], acc[4], 0, 0, 0);
            acc[5] = __builtin_amdgcn_mfma_f32_16x16x32_f16(a, Bf[5][kt], acc[5], 0, 0, 0);
        }

        // ---- gates hf0 (cols 32w+i) ----
#pragma unroll
        for (int r = 0; r < 4; ++r) {
            const float z  = sigmoidf_((float)x0[0][r] + acc[0][r]);
            const float rg = sigmoidf_((float)x0[1][r] + acc[1][r]);
            const float hh = tanhf_((float)x0[2][r] + rg * (acc[2][r] + bh[0]));
            float hn = z * hprev[0][r] + (1.0f - z) * hh;
            hn = ((m4 >> (8 * r)) & 0xff) ? hn : hprev[0][r];
            hprev[0][r] = hn;
            const int bt = 4 * g + r, col = 32 * w + i;
            if (g == 0)
                outp[((size_t)(b0 + r) * os + obase + tl) * HID + col] = hn;
            wr[(w * 64 + (i >> 3) * 16 + bt) * 8 + (i & 7)] = (_Float16)hn;
        }
        // ---- gates hf1 (cols 32w+16+i) ----
#pragma unroll
        for (int r = 0; r < 4; ++r) {
            const float z  = sigmoidf_((float)x1[0][r] + acc[3][r]);
            const float rg = sigmoidf_((float)x1[1][r] + acc[4][r]);
            const float hh = tanhf_((float)x1[2][r] + rg * (acc[5][r] + bh[1]));
            float hn = z * hprev[1][r] + (1.0f - z) * hh;
            hn = ((m4 >> (8 * r)) & 0xff) ? hn : hprev[1][r];
            hprev[1][r] = hn;
            const int bt = 4 * g + r, col = 32 * w + 16 + i;
            if (g == 0)
                outp[((size_t)(b0 + r) * os + obase + tl) * HID + col] = hn;
            wr[(w * 64 + (2 + (i >> 3)) * 16 + bt) * 8 + (i & 7)] = (_Float16)hn;
        }
        // LDS-only barrier: skip vmcnt(0) drain of xp loads / out stores
        asm volatile("s_waitcnt lgkmcnt(0)\n\ts_barrier" ::: "memory");
    }

    __builtin_amdgcn_s_setprio(0);

    if (g == 0) {
#pragma unroll
        for (int hf = 0; hf < 2; ++hf)
#pragma unroll
            for (int r = 0; r < 4; ++r) {
                const int col = 32 * w + hf * 16 + i;
                hstate[(size_t)(b0 + r) * HID + col] = hprev[hf][r];
                if (hfinal) hfinal[(size_t)(b0 + r) * HID + col] = hprev[hf][r];
            }
    }
}

// ---------------------------------------------------------------------------
// GEMM body (fp32, f16 output): xp[r,n] = bias(n) + sum_k Yc[r,k]*W[k,n]
// 512 threads, 64x128 tile, BK=16, 4x4 micro-tile. e: bx=e/6, by=e%6.
// ---------------------------------------------------------------------------
__device__ __forceinline__ void gemm_body(
    char* smem, const float* __restrict__ Yc, const float* __restrict__ W,
    const float* __restrict__ bb, _Float16* __restrict__ xpout, int e)
{
    float (*As)[68]  = (float (*)[68])smem;                    // [16][68]
    float (*Bs)[128] = (float (*)[128])(smem + 16 * 68 * 4);   // [16][128]

    const int bx = e / 6, by = e % 6;
    const int m0 = bx * 64, n0 = by * 128;
    const int tid = threadIdx.x;
    const int lrA = tid >> 3, lcA = (tid & 7) * 2;
    const int lrB = tid >> 5, lcB = (tid & 31) * 4;
    const int ty = tid >> 5, tx = tid & 31;

    float acc[4][4] = {};

    for (int k0 = 0; k0 < HID; k0 += 16) {
        float2 av = *(const float2*)(Yc + (size_t)(m0 + lrA) * HID + k0 + lcA);
        As[lcA][lrA] = av.x; As[lcA + 1][lrA] = av.y;
        float4 bv = *(const float4*)(W + (size_t)(k0 + lrB) * GATE + n0 + lcB);
        *(float4*)&Bs[lrB][lcB] = bv;
        __syncthreads();
#pragma unroll
        for (int k = 0; k < 16; ++k) {
            float4 a  = *(const float4*)&As[k][ty * 4];
            float4 bq = *(const float4*)&Bs[k][tx * 4];
            float a_[4] = {a.x, a.y, a.z, a.w};
            float b_[4] = {bq.x, bq.y, bq.z, bq.w};
#pragma unroll
            for (int ii = 0; ii < 4; ++ii)
#pragma unroll
                for (int jj = 0; jj < 4; ++jj)
                    acc[ii][jj] += a_[ii] * b_[jj];
        }
        __syncthreads();
    }

#pragma unroll
    for (int ii = 0; ii < 4; ++ii) {
        const int row = m0 + ty * 4 + ii;
        union { _Float16 h[4]; float2 f2; } u;
#pragma unroll
        for (int jj = 0; jj < 4; ++jj) {
            const int n = n0 + tx * 4 + jj;
            u.h[jj] = (_Float16)(acc[ii][jj] + bb[n] + ((n < 2 * HID) ? bb[GATE + n] : 0.0f));
        }
        *(float2*)&xpout[(size_t)row * GATE + n0 + tx * 4] = u.f2;
    }
    __syncthreads();   // protect As/Bs for the next work item
}

// ---------------------------------------------------------------------------
// Layer-0 projection body (f16 output): one item per batch element.
// ---------------------------------------------------------------------------
__device__ __forceinline__ void xp0_body(
    const int* __restrict__ batch, const float* __restrict__ W0,
    const float* __restrict__ bb, _Float16* __restrict__ xpout, int t0, int b)
{
    const int tid = threadIdx.x;
    for (int tl = 0; tl < TC; ++tl) {
        const int* xr = batch + ((size_t)b * SEQ + t0 + tl) * FEAT;
        float xf[FEAT];
#pragma unroll
        for (int f = 0; f < FEAT; ++f) xf[f] = (float)xr[f];
        for (int cc = tid; cc < GATE; cc += NT) {
            float acc = bb[cc] + ((cc < 2 * HID) ? bb[GATE + cc] : 0.0f);
#pragma unroll
            for (int f = 0; f < FEAT; ++f)
                acc += xf[f] * W0[f * GATE + cc];
            xpout[((size_t)b * TC + tl) * GATE + cc] = (_Float16)acc;
        }
    }
}

// ---------------------------------------------------------------------------
// Fused pipeline kernel, EXACTLY 256 blocks (1 per CU -> GRU contention-free).
// Launch d:
//   bid  0-15 : gru layer0, chunk d       (b0 = bid*4)
//   bid 16-31 : gru layer1, chunk d-2
//   bid 32-47 : gru layer2, chunk d-4
//   bid 48-255: worker, 4 items each of 832:
//               item 0-63    xp0 chunk d+1 (batch = item)
//               item 64-447  gemm L1 chunk d-1 (tile = item-64)
//               item 448-831 gemm L2 chunk d-3 (tile = item-448)
// ---------------------------------------------------------------------------
__global__ __launch_bounds__(NT, 1) void k_fused(Params P, int d)
{
    __shared__ __align__(16) char smem[17408];
    const int bid = blockIdx.x;

    if (bid < NGRU) {
        const int c = d;
        if (c >= 0 && c <= LASTC)
            gru_body(smem, (c & 1) ? P.xp0b : P.xp0a, P.Bf0, P.b0, P.batch,
                     (c & 1) ? P.y0b : P.y0a, TC, 0, nullptr, P.h0, c * TC, bid * GB);
    } else if (bid < 2 * NGRU) {
        const int c = d - 2;
        if (c >= 0 && c <= LASTC)
            gru_body(smem, (c & 1) ? P.xp1b : P.xp1a, P.Bf1, P.b1, P.batch,
                     (c & 1) ? P.y1b : P.y1a, TC, 0, nullptr, P.h1, c * TC, (bid - NGRU) * GB);
    } else if (bid < 3 * NGRU) {
        const int c = d - 4;
        if (c >= 0 && c <= LASTC)
            gru_body(smem, (c & 1) ? P.xp2b : P.xp2a, P.Bf2, P.b2, P.batch,
                     P.out, SEQ, c * TC, (c == LASTC) ? P.hfin : nullptr,
                     P.h2, c * TC, (bid - 2 * NGRU) * GB);
    } else {
        for (int item = bid - 48; item < NITEM; item += NWRK) {
            if (item < 64) {
                const int c = d + 1;
                if (c >= 0 && c <= LASTC)
                    xp0_body(P.batch, P.W0, P.b0, (c & 1) ? P.xp0b : P.xp0a,
                             c * TC, item);
            } else if (item < 448) {
                const int c = d - 1;
                if (c >= 0 && c <= LASTC)
                    gemm_body(smem, (c & 1) ? P.y0b : P.y0a, P.W1, P.b1,
                              (c & 1) ? P.xp1b : P.xp1a, item - 64);
            } else {
                const int c = d - 3;
                if (c >= 0 && c <= LASTC)
                    gemm_body(smem, (c & 1) ? P.y1b : P.y1a, P.W2, P.b2,
                              (c & 1) ? P.xp2b : P.xp2a, item - 448);
            }
        }
    }
}

// ---------------------------------------------------------------------------
extern "C" void kernel_launch(void* const* d_in, const int* in_sizes, int n_in,
                              void* d_out, int out_size, void* d_ws, size_t ws_size,
                              hipStream_t stream)
{
    const int*   batch = (const int*)d_in[0];
    const float* W0 = (const float*)d_in[1];
    const float* U0 = (const float*)d_in[2];
    const float* b0 = (const float*)d_in[3];
    const float* W1 = (const float*)d_in[4];
    const float* U1 = (const float*)d_in[5];
    const float* b1 = (const float*)d_in[6];
    const float* W2 = (const float*)d_in[7];
    const float* U2 = (const float*)d_in[8];
    const float* b2 = (const float*)d_in[9];

    float* out  = (float*)d_out;
    float* hfin = out + (size_t)BATCH * SEQ * HID;

    const size_t XPB = (size_t)BATCH * TC * GATE * 2;   // f16 xp chunk bytes
    const size_t YB  = (size_t)BATCH * TC * HID * 4;    // fp32 y chunk bytes
    const size_t HB  = (size_t)BATCH * HID * 4;
    const size_t BFB = (size_t)48 * 8 * 64 * 4 * 4;     // B-frag bytes

    char* p = (char*)d_ws;
    auto alloc = [&](size_t bytes) { char* q = p; p += (bytes + 255) & ~(size_t)255; return q; };
    _Float16* xp0a = (_Float16*)alloc(XPB);
    _Float16* xp0b = (_Float16*)alloc(XPB);
    _Float16* xp1a = (_Float16*)alloc(XPB);
    _Float16* xp1b = (_Float16*)alloc(XPB);
    _Float16* xp2a = (_Float16*)alloc(XPB);
    _Float16* xp2b = (_Float16*)alloc(XPB);
    float* y0a = (float*)alloc(YB);
    float* y0b = (float*)alloc(YB);
    float* y1a = (float*)alloc(YB);
    float* y1b = (float*)alloc(YB);
    float* h0  = (float*)alloc(HB);
    float* h1  = (float*)alloc(HB);
    float* h2  = (float*)alloc(HB);
    float* Bf0 = (float*)alloc(BFB);
    float* Bf1 = (float*)alloc(BFB);
    float* Bf2 = (float*)alloc(BFB);

    dim3 gpack(48 * 8 * 64 / 256), bpack(256);
    k_packB<<<gpack, bpack, 0, stream>>>(U0, Bf0);
    k_packB<<<gpack, bpack, 0, stream>>>(U1, Bf1);
    k_packB<<<gpack, bpack, 0, stream>>>(U2, Bf2);

    Params P;
    P.batch = batch;
    P.W0 = W0; P.b0 = b0; P.W1 = W1; P.b1 = b1; P.W2 = W2; P.b2 = b2;
    P.Bf0 = Bf0; P.Bf1 = Bf1; P.Bf2 = Bf2;
    P.xp0a = xp0a; P.xp0b = xp0b; P.xp1a = xp1a; P.xp1b = xp1b;
    P.xp2a = xp2a; P.xp2b = xp2b;
    P.y0a = y0a; P.y0b = y0b; P.y1a = y1a; P.y1b = y1b;
    P.h0 = h0; P.h1 = h1; P.h2 = h2;
    P.out = out; P.hfin = hfin;

    for (int d = -1; d <= LASTC + 4; ++d)
        k_fused<<<dim3(256), dim3(NT), 0, stream>>>(P, d);
}

// Round 10
// 2613.382 us; speedup vs baseline: 2.3585x; 1.7600x over previous
//
#include <hip/hip_runtime.h>
#include <cstdint>

#define BATCH 64
#define SEQ   1024
#define FEAT  16
#define HID   256
#define GATE  768    // 3*HID
#define TC    64     // time-chunk length
#define LASTC 15     // SEQ/TC - 1
#define NT    512    // block threads (8 waves)
#define NWRK  64     // worker blocks
#define NITEM 832    // 64 xp0 + 384 gemm1 + 384 gemm2

typedef _Float16 f16x8 __attribute__((ext_vector_type(8)));
typedef float    f32x4 __attribute__((ext_vector_type(4)));

__device__ __forceinline__ float sigmoidf_(float x) { return 1.0f / (1.0f + __expf(-x)); }
__device__ __forceinline__ float tanhf_(float x)    { return 2.0f / (1.0f + __expf(-2.0f * x)) - 1.0f; }

// ---------------------------------------------------------------------------
// Pack a [HID][GATE] fp32 matrix (U or W1/W2) into MFMA B-fragments (f16).
// Fragment (ct, kt, lane): 8 f16 = M[kt*32 + (lane>>4)*8 + e][ct*16 + (lane&15)]
// at out[((ct*8 + kt)*64 + lane) * 4].  (Verified convention from rounds 5-9.)
// ---------------------------------------------------------------------------
__global__ __launch_bounds__(256) void k_packB(const float* __restrict__ U,
                                               float* __restrict__ Bfrag)
{
    const int tid = blockIdx.x * 256 + threadIdx.x;   // < 48*8*64
    const int ct   = tid >> 9;
    const int kt   = (tid >> 6) & 7;
    const int lane = tid & 63;
    const int g = lane >> 4, i = lane & 15;
    const int col = ct * 16 + i;
    const int k0  = kt * 32 + g * 8;
    union { f16x8 v; float4 f; } u;
#pragma unroll
    for (int e = 0; e < 8; ++e)
        u.v[e] = (_Float16)U[(size_t)(k0 + e) * GATE + col];
    *(float4*)(Bfrag + (size_t)tid * 4) = u.f;
}

// ---------------------------------------------------------------------------
struct Params {
    const int*   batch;
    const float *W0, *b0, *b1, *b2;
    const float *Bf0, *Bf1, *Bf2;   // packed U0,U1,U2
    const float *Wp1, *Wp2;         // packed W1,W2
    _Float16 *xp0a, *xp0b, *xp1a, *xp1b, *xp2a, *xp2b;  // f16 xp rings
    _Float16 *y0a, *y0b, *y1a, *y1b;                     // f16 y rings
    float *h0, *h1, *h2;
    float *out, *hfin;
};

// ---------------------------------------------------------------------------
// GRU body: R5-proven broadcast-A MFMA version. One block = ONE batch element.
// 8 waves; wave w owns h-cols [32w,32w+32). A = h broadcast into all 16 rows
// (16-lane-broadcast LDS read); B = U fragments register-resident (6 ct x 8 kt).
// All C rows equal -> lane (g=l>>4,i=l&15) takes acc[.][0] for col
// c = 32w + i + 16*(g&1); lanes l<32 store h/out. 1 barrier/step,
// double-buffered f16 h in LDS. Gate math ~0.5 outputs/lane (spread wide).
// yout!=null: write f16 y ring [b][tl][HID]; else fp32 out [b][SEQ][HID].
// ---------------------------------------------------------------------------
__device__ __forceinline__ void gru_body(
    char* smem, const _Float16* __restrict__ xp, const float* __restrict__ Bfrag,
    const float* __restrict__ bb, const int* __restrict__ batch,
    _Float16* __restrict__ yout, float* __restrict__ fout, int obase,
    float* __restrict__ hfinal, float* __restrict__ hstate, int t0, int b)
{
    _Float16 (*hbuf)[HID] = (_Float16 (*)[HID])smem;   // [2][256]

    const int T  = threadIdx.x;
    const int w  = T >> 6;
    const int l  = T & 63;
    const int g  = l >> 4;
    const int i  = l & 15;
    const int g1 = g & 1;
    const int c  = 32 * w + i + 16 * g1;   // this lane's gate/h column

    // ---- register-resident B fragments: 6 col-tiles x 8 k-tiles ----
    f16x8 Bf[6][8];
    {
        const int cts[6] = {2 * w, 16 + 2 * w, 32 + 2 * w,
                            2 * w + 1, 17 + 2 * w, 33 + 2 * w};
#pragma unroll
        for (int ci = 0; ci < 6; ++ci)
#pragma unroll
            for (int kt = 0; kt < 8; ++kt) {
                float4 v = *(const float4*)(Bfrag + ((size_t)(cts[ci] * 8 + kt) * 64 + l) * 4);
                Bf[ci][kt] = __builtin_bit_cast(f16x8, v);
            }
    }

    const float bh = bb[GATE + 2 * HID + c];   // recurrent bias, h gate only

    float hprev = (t0 == 0) ? 0.0f : hstate[b * HID + c];
    if (l < 32) hbuf[0][32 * w + l] = (_Float16)hprev;
    __syncthreads();

    for (int tl = 0; tl < TC; ++tl) {
        // xp/mask loads up front; consumed after the mfma chain (latency hidden)
        const _Float16* xrow = xp + ((size_t)b * TC + tl) * GATE;
        const float xz = (float)xrow[c];
        const float xr = (float)xrow[HID + c];
        const float xh = (float)xrow[2 * HID + c];
        const int   mf = batch[((size_t)b * SEQ + t0 + tl) * FEAT + (FEAT - 1)];

        const _Float16* rd = hbuf[tl & 1];

        f32x4 az0 = {0.f, 0.f, 0.f, 0.f}, ar0 = az0, ah0 = az0;
        f32x4 az1 = az0, ar1 = az0, ah1 = az0;
#pragma unroll
        for (int kt = 0; kt < 8; ++kt) {
            const f16x8 a = *(const f16x8*)(rd + kt * 32 + g * 8);  // 16-lane broadcast
            az0 = __builtin_amdgcn_mfma_f32_16x16x32_f16(a, Bf[0][kt], az0, 0, 0, 0);
            ar0 = __builtin_amdgcn_mfma_f32_16x16x32_f16(a, Bf[1][kt], ar0, 0, 0, 0);
            ah0 = __builtin_amdgcn_mfma_f32_16x16x32_f16(a, Bf[2][kt], ah0, 0, 0, 0);
            az1 = __builtin_amdgcn_mfma_f32_16x16x32_f16(a, Bf[3][kt], az1, 0, 0, 0);
            ar1 = __builtin_amdgcn_mfma_f32_16x16x32_f16(a, Bf[4][kt], ar1, 0, 0, 0);
            ah1 = __builtin_amdgcn_mfma_f32_16x16x32_f16(a, Bf[5][kt], ah1, 0, 0, 0);
        }

        const float az = g1 ? az1[0] : az0[0];
        const float ar = g1 ? ar1[0] : ar0[0];
        const float ah = g1 ? ah1[0] : ah0[0];

        const float z  = sigmoidf_(xz + az);
        const float r  = sigmoidf_(xr + ar);
        const float hh = tanhf_(xh + r * (ah + bh));
        float hn = z * hprev + (1.0f - z) * hh;
        hn = (mf != -1) ? hn : hprev;
        hprev = hn;

        if (l < 32) {
            if (yout)
                yout[((size_t)b * TC + tl) * HID + 32 * w + l] = (_Float16)hn;
            else
                fout[((size_t)b * SEQ + obase + tl) * HID + 32 * w + l] = hn;
            hbuf[(tl & 1) ^ 1][32 * w + l] = (_Float16)hn;
        }
        __syncthreads();
    }

    if (l < 32) {
        hstate[b * HID + 32 * w + l] = hprev;
        if (hfinal) hfinal[b * HID + 32 * w + l] = hprev;
    }
}

// ---------------------------------------------------------------------------
// MFMA GEMM body: xp[r,n] = bias(n) + sum_k Yc[r,k]*W[k,n], f16 in/out.
// Item e = one 64x128 tile: m0 = (e/6)*64 (one batch's 64 time-rows),
// by = e%6. 8 waves; wave w owns col-tile ct = by*8 + w.
// A-frag lane l: row m0 + rt*16 + (l&15), k = kt*32 + (l>>4)*8 (same k-map
// as packed B -> permutation cancels; same convention verified in gru).
// D lane l reg r -> row m0 + rt*16 + 4*(l>>4) + r, col ct*16 + (l&15).
// ---------------------------------------------------------------------------
__device__ __forceinline__ void gemm_mfma_body(
    const _Float16* __restrict__ Yc, const float* __restrict__ Wp,
    const float* __restrict__ bb, _Float16* __restrict__ xpout, int e)
{
    const int T = threadIdx.x;
    const int w = T >> 6;
    const int l = T & 63;
    const int g = l >> 4;
    const int i = l & 15;
    const int m0 = (e / 6) * 64;
    const int ct = (e % 6) * 8 + w;

    f16x8 Bf[8];
#pragma unroll
    for (int kt = 0; kt < 8; ++kt) {
        float4 v = *(const float4*)(Wp + ((size_t)(ct * 8 + kt) * 64 + l) * 4);
        Bf[kt] = __builtin_bit_cast(f16x8, v);
    }

    f16x8 Af[4][8];
#pragma unroll
    for (int rt = 0; rt < 4; ++rt)
#pragma unroll
        for (int kt = 0; kt < 8; ++kt)
            Af[rt][kt] = *(const f16x8*)(Yc + (size_t)(m0 + rt * 16 + i) * HID
                                            + kt * 32 + g * 8);

    f32x4 acc[4];
#pragma unroll
    for (int rt = 0; rt < 4; ++rt) acc[rt] = (f32x4){0.f, 0.f, 0.f, 0.f};
#pragma unroll
    for (int kt = 0; kt < 8; ++kt) {
        acc[0] = __builtin_amdgcn_mfma_f32_16x16x32_f16(Af[0][kt], Bf[kt], acc[0], 0, 0, 0);
        acc[1] = __builtin_amdgcn_mfma_f32_16x16x32_f16(Af[1][kt], Bf[kt], acc[1], 0, 0, 0);
        acc[2] = __builtin_amdgcn_mfma_f32_16x16x32_f16(Af[2][kt], Bf[kt], acc[2], 0, 0, 0);
        acc[3] = __builtin_amdgcn_mfma_f32_16x16x32_f16(Af[3][kt], Bf[kt], acc[3], 0, 0, 0);
    }

    const int n = ct * 16 + i;
    const float bias = bb[n] + ((n < 2 * HID) ? bb[GATE + n] : 0.0f);
#pragma unroll
    for (int rt = 0; rt < 4; ++rt)
#pragma unroll
        for (int r = 0; r < 4; ++r)
            xpout[(size_t)(m0 + rt * 16 + 4 * g + r) * GATE + n] =
                (_Float16)(acc[rt][r] + bias);
}

// ---------------------------------------------------------------------------
// Layer-0 projection body (f16 output): one item per batch element.
// ---------------------------------------------------------------------------
__device__ __forceinline__ void xp0_body(
    const int* __restrict__ batch, const float* __restrict__ W0,
    const float* __restrict__ bb, _Float16* __restrict__ xpout, int t0, int b)
{
    const int tid = threadIdx.x;
    for (int tl = 0; tl < TC; ++tl) {
        const int* xr = batch + ((size_t)b * SEQ + t0 + tl) * FEAT;
        float xf[FEAT];
#pragma unroll
        for (int f = 0; f < FEAT; ++f) xf[f] = (float)xr[f];
        for (int cc = tid; cc < GATE; cc += NT) {
            float acc = bb[cc] + ((cc < 2 * HID) ? bb[GATE + cc] : 0.0f);
#pragma unroll
            for (int f = 0; f < FEAT; ++f)
                acc += xf[f] * W0[f * GATE + cc];
            xpout[((size_t)b * TC + tl) * GATE + cc] = (_Float16)acc;
        }
    }
}

// ---------------------------------------------------------------------------
// Fused pipeline kernel, EXACTLY 256 blocks (1 per CU; VGPR>128 forces 1 blk/CU).
// Launch d:
//   bid   0- 63 : gru layer0 chunk d     (batch = bid)
//   bid  64-127 : gru layer1 chunk d-2
//   bid 128-191 : gru layer2 chunk d-4
//   bid 192-255 : worker, 13 items each of 832:
//                 item 0-63    xp0 chunk d+1 (batch = item)
//                 item 64-447  MFMA-gemm L1 chunk d-1 (tile = item-64)
//                 item 448-831 MFMA-gemm L2 chunk d-3 (tile = item-448)
// ---------------------------------------------------------------------------
__global__ __launch_bounds__(NT, 1) void k_fused(Params P, int d)
{
    __shared__ __align__(16) char smem[2 * HID * 2];
    const int bid = blockIdx.x;

    if (bid < 64) {
        const int c = d;
        if (c >= 0 && c <= LASTC)
            gru_body(smem, (c & 1) ? P.xp0b : P.xp0a, P.Bf0, P.b0, P.batch,
                     (c & 1) ? P.y0b : P.y0a, nullptr, 0, nullptr, P.h0,
                     c * TC, bid);
    } else if (bid < 128) {
        const int c = d - 2;
        if (c >= 0 && c <= LASTC)
            gru_body(smem, (c & 1) ? P.xp1b : P.xp1a, P.Bf1, P.b1, P.batch,
                     (c & 1) ? P.y1b : P.y1a, nullptr, 0, nullptr, P.h1,
                     c * TC, bid - 64);
    } else if (bid < 192) {
        const int c = d - 4;
        if (c >= 0 && c <= LASTC)
            gru_body(smem, (c & 1) ? P.xp2b : P.xp2a, P.Bf2, P.b2, P.batch,
                     nullptr, P.out, c * TC, (c == LASTC) ? P.hfin : nullptr,
                     P.h2, c * TC, bid - 128);
    } else {
        for (int item = bid - 192; item < NITEM; item += NWRK) {
            if (item < 64) {
                const int c = d + 1;
                if (c >= 0 && c <= LASTC)
                    xp0_body(P.batch, P.W0, P.b0, (c & 1) ? P.xp0b : P.xp0a,
                             c * TC, item);
            } else if (item < 448) {
                const int c = d - 1;
                if (c >= 0 && c <= LASTC)
                    gemm_mfma_body((c & 1) ? P.y0b : P.y0a, P.Wp1, P.b1,
                                   (c & 1) ? P.xp1b : P.xp1a, item - 64);
            } else {
                const int c = d - 3;
                if (c >= 0 && c <= LASTC)
                    gemm_mfma_body((c & 1) ? P.y1b : P.y1a, P.Wp2, P.b2,
                                   (c & 1) ? P.xp2b : P.xp2a, item - 448);
            }
        }
    }
}

// ---------------------------------------------------------------------------
extern "C" void kernel_launch(void* const* d_in, const int* in_sizes, int n_in,
                              void* d_out, int out_size, void* d_ws, size_t ws_size,
                              hipStream_t stream)
{
    const int*   batch = (const int*)d_in[0];
    const float* W0 = (const float*)d_in[1];
    const float* U0 = (const float*)d_in[2];
    const float* b0 = (const float*)d_in[3];
    const float* W1 = (const float*)d_in[4];
    const float* U1 = (const float*)d_in[5];
    const float* b1 = (const float*)d_in[6];
    const float* W2 = (const float*)d_in[7];
    const float* U2 = (const float*)d_in[8];
    const float* b2 = (const float*)d_in[9];

    float* out  = (float*)d_out;
    float* hfin = out + (size_t)BATCH * SEQ * HID;

    const size_t XPB = (size_t)BATCH * TC * GATE * 2;   // f16 xp chunk bytes
    const size_t YB  = (size_t)BATCH * TC * HID * 2;    // f16 y chunk bytes
    const size_t HB  = (size_t)BATCH * HID * 4;
    const size_t BFB = (size_t)48 * 8 * 64 * 4 * 4;     // packed-frag bytes

    char* p = (char*)d_ws;
    auto alloc = [&](size_t bytes) { char* q = p; p += (bytes + 255) & ~(size_t)255; return q; };
    _Float16* xp0a = (_Float16*)alloc(XPB);
    _Float16* xp0b = (_Float16*)alloc(XPB);
    _Float16* xp1a = (_Float16*)alloc(XPB);
    _Float16* xp1b = (_Float16*)alloc(XPB);
    _Float16* xp2a = (_Float16*)alloc(XPB);
    _Float16* xp2b = (_Float16*)alloc(XPB);
    _Float16* y0a  = (_Float16*)alloc(YB);
    _Float16* y0b  = (_Float16*)alloc(YB);
    _Float16* y1a  = (_Float16*)alloc(YB);
    _Float16* y1b  = (_Float16*)alloc(YB);
    float* h0  = (float*)alloc(HB);
    float* h1  = (float*)alloc(HB);
    float* h2  = (float*)alloc(HB);
    float* Bf0 = (float*)alloc(BFB);
    float* Bf1 = (float*)alloc(BFB);
    float* Bf2 = (float*)alloc(BFB);
    float* Wp1 = (float*)alloc(BFB);
    float* Wp2 = (float*)alloc(BFB);

    dim3 gpack(48 * 8 * 64 / 256), bpack(256);
    k_packB<<<gpack, bpack, 0, stream>>>(U0, Bf0);
    k_packB<<<gpack, bpack, 0, stream>>>(U1, Bf1);
    k_packB<<<gpack, bpack, 0, stream>>>(U2, Bf2);
    k_packB<<<gpack, bpack, 0, stream>>>(W1, Wp1);
    k_packB<<<gpack, bpack, 0, stream>>>(W2, Wp2);

    Params P;
    P.batch = batch;
    P.W0 = W0; P.b0 = b0; P.b1 = b1; P.b2 = b2;
    P.Bf0 = Bf0; P.Bf1 = Bf1; P.Bf2 = Bf2;
    P.Wp1 = Wp1; P.Wp2 = Wp2;
    P.xp0a = xp0a; P.xp0b = xp0b; P.xp1a = xp1a; P.xp1b = xp1b;
    P.xp2a = xp2a; P.xp2b = xp2b;
    P.y0a = y0a; P.y0b = y0b; P.y1a = y1a; P.y1b = y1b;
    P.h0 = h0; P.h1 = h1; P.h2 = h2;
    P.out = out; P.hfin = hfin;

    for (int d = -1; d <= LASTC + 4; ++d)
        k_fused<<<dim3(256), dim3(NT), 0, stream>>>(P, d);
}

// Round 11
// 1425.677 us; speedup vs baseline: 4.3233x; 1.8331x over previous
//
#include <hip/hip_runtime.h>
#include <cstdint>

#define BATCH 64
#define SEQ   1024
#define FEAT  16
#define HID   256
#define GATE  768    // 3*HID
#define TC    64     // time-chunk length
#define LASTC 15     // SEQ/TC - 1
#define NT    512    // block threads (8 waves)
#define NWRK  64     // worker blocks
#define NITEM 192    // 64 xp0 + 64 gemm1 + 64 gemm2 (full-N M-tile items)

typedef _Float16 f16x8 __attribute__((ext_vector_type(8)));
typedef float    f32x4 __attribute__((ext_vector_type(4)));

__device__ __forceinline__ float sigmoidf_(float x) { return 1.0f / (1.0f + __expf(-x)); }
__device__ __forceinline__ float tanhf_(float x)    { return 2.0f / (1.0f + __expf(-2.0f * x)) - 1.0f; }

// ---------------------------------------------------------------------------
// Pack a [HID][GATE] fp32 matrix (U or W1/W2) into MFMA B-fragments (f16).
// Fragment (ct, kt, lane): 8 f16 = M[kt*32 + (lane>>4)*8 + e][ct*16 + (lane&15)]
// at out[((ct*8 + kt)*64 + lane) * 4].  (Verified convention, rounds 5-10.)
// ---------------------------------------------------------------------------
__global__ __launch_bounds__(256) void k_packB(const float* __restrict__ U,
                                               float* __restrict__ Bfrag)
{
    const int tid = blockIdx.x * 256 + threadIdx.x;   // < 48*8*64
    const int ct   = tid >> 9;
    const int kt   = (tid >> 6) & 7;
    const int lane = tid & 63;
    const int g = lane >> 4, i = lane & 15;
    const int col = ct * 16 + i;
    const int k0  = kt * 32 + g * 8;
    union { f16x8 v; float4 f; } u;
#pragma unroll
    for (int e = 0; e < 8; ++e)
        u.v[e] = (_Float16)U[(size_t)(k0 + e) * GATE + col];
    *(float4*)(Bfrag + (size_t)tid * 4) = u.f;
}

// ---------------------------------------------------------------------------
struct Params {
    const int*   batch;
    const float *W0, *b0, *b1, *b2;
    const float *Bf0, *Bf1, *Bf2;   // packed U0,U1,U2
    const float *Wp1, *Wp2;         // packed W1,W2
    _Float16 *xp0a, *xp0b, *xp1a, *xp1b, *xp2a, *xp2b;  // f16 xp rings
    _Float16 *y0a, *y0b, *y1a, *y1b;                     // f16 y rings
    float *h0, *h1, *h2;
    float *out, *hfin;
};

// ---------------------------------------------------------------------------
// GRU body: broadcast-A MFMA (R5/R10-proven) + 1-step-ahead xp/mask register
// prefetch + LDS-only barrier (lgkmcnt(0) + s_barrier) so the prefetched
// global loads stay in flight ACROSS the barrier (plain __syncthreads would
// drain vmcnt(0) every step and re-expose HBM latency).
// One block = ONE batch element; 8 waves; wave w owns h-cols [32w,32w+32).
// ---------------------------------------------------------------------------
__device__ __forceinline__ void gru_body(
    char* smem, const _Float16* __restrict__ xp, const float* __restrict__ Bfrag,
    const float* __restrict__ bb, const int* __restrict__ batch,
    _Float16* __restrict__ yout, float* __restrict__ fout, int obase,
    float* __restrict__ hfinal, float* __restrict__ hstate, int t0, int b)
{
    _Float16 (*hbuf)[HID] = (_Float16 (*)[HID])smem;   // [2][256]

    const int T  = threadIdx.x;
    const int w  = T >> 6;
    const int l  = T & 63;
    const int g  = l >> 4;
    const int i  = l & 15;
    const int g1 = g & 1;
    const int c  = 32 * w + i + 16 * g1;   // this lane's gate/h column

    // ---- register-resident B fragments: 6 col-tiles x 8 k-tiles ----
    f16x8 Bf[6][8];
    {
        const int cts[6] = {2 * w, 16 + 2 * w, 32 + 2 * w,
                            2 * w + 1, 17 + 2 * w, 33 + 2 * w};
#pragma unroll
        for (int ci = 0; ci < 6; ++ci)
#pragma unroll
            for (int kt = 0; kt < 8; ++kt) {
                float4 v = *(const float4*)(Bfrag + ((size_t)(cts[ci] * 8 + kt) * 64 + l) * 4);
                Bf[ci][kt] = __builtin_bit_cast(f16x8, v);
            }
    }

    const float bh = bb[GATE + 2 * HID + c];   // recurrent bias, h gate only

    float hprev = (t0 == 0) ? 0.0f : hstate[b * HID + c];
    if (l < 32) hbuf[0][32 * w + l] = (_Float16)hprev;

    // ---- prologue prefetch: step 0 xp + mask ----
    _Float16 nxz, nxr, nxh; int nmf;
    {
        const _Float16* xrow = xp + ((size_t)b * TC + 0) * GATE;
        nxz = xrow[c]; nxr = xrow[HID + c]; nxh = xrow[2 * HID + c];
        nmf = batch[((size_t)b * SEQ + t0) * FEAT + (FEAT - 1)];
    }
    __syncthreads();   // initial full barrier (once)

    for (int tl = 0; tl < TC; ++tl) {
        // consume prefetched values; immediately issue next step's loads
        const _Float16 cxz = nxz, cxr = nxr, cxh = nxh;
        const int cmf = nmf;
        {
            const int tn = (tl + 1 < TC) ? tl + 1 : tl;
            const _Float16* xrow = xp + ((size_t)b * TC + tn) * GATE;
            nxz = xrow[c]; nxr = xrow[HID + c]; nxh = xrow[2 * HID + c];
            nmf = batch[((size_t)b * SEQ + t0 + tn) * FEAT + (FEAT - 1)];
        }

        const _Float16* rd = hbuf[tl & 1];

        f32x4 az0 = {0.f, 0.f, 0.f, 0.f}, ar0 = az0, ah0 = az0;
        f32x4 az1 = az0, ar1 = az0, ah1 = az0;
#pragma unroll
        for (int kt = 0; kt < 8; ++kt) {
            const f16x8 a = *(const f16x8*)(rd + kt * 32 + g * 8);  // 16-lane broadcast
            az0 = __builtin_amdgcn_mfma_f32_16x16x32_f16(a, Bf[0][kt], az0, 0, 0, 0);
            ar0 = __builtin_amdgcn_mfma_f32_16x16x32_f16(a, Bf[1][kt], ar0, 0, 0, 0);
            ah0 = __builtin_amdgcn_mfma_f32_16x16x32_f16(a, Bf[2][kt], ah0, 0, 0, 0);
            az1 = __builtin_amdgcn_mfma_f32_16x16x32_f16(a, Bf[3][kt], az1, 0, 0, 0);
            ar1 = __builtin_amdgcn_mfma_f32_16x16x32_f16(a, Bf[4][kt], ar1, 0, 0, 0);
            ah1 = __builtin_amdgcn_mfma_f32_16x16x32_f16(a, Bf[5][kt], ah1, 0, 0, 0);
        }

        const float az = g1 ? az1[0] : az0[0];
        const float ar = g1 ? ar1[0] : ar0[0];
        const float ah = g1 ? ah1[0] : ah0[0];

        const float z  = sigmoidf_((float)cxz + az);
        const float r  = sigmoidf_((float)cxr + ar);
        const float hh = tanhf_((float)cxh + r * (ah + bh));
        float hn = z * hprev + (1.0f - z) * hh;
        hn = (cmf != -1) ? hn : hprev;
        hprev = hn;

        if (l < 32) {
            if (yout)
                yout[((size_t)b * TC + tl) * HID + 32 * w + l] = (_Float16)hn;
            else
                fout[((size_t)b * SEQ + obase + tl) * HID + 32 * w + l] = hn;
            hbuf[(tl & 1) ^ 1][32 * w + l] = (_Float16)hn;
        }
        // LDS-only barrier: prefetched global loads stay in flight
        asm volatile("s_waitcnt lgkmcnt(0)\n\ts_barrier" ::: "memory");
    }

    if (l < 32) {
        hstate[b * HID + 32 * w + l] = hprev;
        if (hfinal) hfinal[b * HID + 32 * w + l] = hprev;
    }
}

// ---------------------------------------------------------------------------
// MFMA GEMM body, full-N M-tile item: xp[mt*64 .. +64][0..768) from
// Yc rows staged ONCE in LDS (padded [64][264] f16 -> ~2-way conflicts),
// killing the 8x per-wave redundant global A reads of the 64x128 version.
// Wave w covers col-tiles ct = 6w..6w+5. Fragment maps identical to the
// verified R10 convention (As[row][k] == Yc[m0+row][k]).
// ---------------------------------------------------------------------------
__device__ __forceinline__ void gemm_mfma_body(
    char* smem, const _Float16* __restrict__ Yc, const float* __restrict__ Wp,
    const float* __restrict__ bb, _Float16* __restrict__ xpout, int mt)
{
    _Float16 (*As)[264] = (_Float16 (*)[264])smem;   // 64 x 264 (pad 8)

    const int T = threadIdx.x;
    const int w = T >> 6;
    const int l = T & 63;
    const int g = l >> 4;
    const int i = l & 15;

    // ---- stage A-tile (64 rows x 256 f16 = 32KB) into LDS ----
    {
        const _Float16* src = Yc + (size_t)mt * TC * HID;
#pragma unroll
        for (int q = 0; q < 4; ++q) {
            const int ch  = T * 4 + q;          // 0..2047 chunks of 16B
            const int row = ch >> 5;
            const int ko  = (ch & 31) * 8;
            *(float4*)&As[row][ko] = *(const float4*)(src + (size_t)row * HID + ko);
        }
    }
    __syncthreads();

    // ---- A fragments from LDS (reused across all 6 ct) ----
    f16x8 Af[4][8];
#pragma unroll
    for (int rt = 0; rt < 4; ++rt)
#pragma unroll
        for (int kt = 0; kt < 8; ++kt)
            Af[rt][kt] = *(const f16x8*)&As[rt * 16 + i][kt * 32 + g * 8];

#pragma unroll
    for (int ci = 0; ci < 6; ++ci) {
        const int ct = w * 6 + ci;
        f16x8 Bfr[8];
#pragma unroll
        for (int kt = 0; kt < 8; ++kt) {
            float4 v = *(const float4*)(Wp + ((size_t)(ct * 8 + kt) * 64 + l) * 4);
            Bfr[kt] = __builtin_bit_cast(f16x8, v);
        }
        f32x4 acc[4];
#pragma unroll
        for (int rt = 0; rt < 4; ++rt) acc[rt] = (f32x4){0.f, 0.f, 0.f, 0.f};
#pragma unroll
        for (int kt = 0; kt < 8; ++kt) {
            acc[0] = __builtin_amdgcn_mfma_f32_16x16x32_f16(Af[0][kt], Bfr[kt], acc[0], 0, 0, 0);
            acc[1] = __builtin_amdgcn_mfma_f32_16x16x32_f16(Af[1][kt], Bfr[kt], acc[1], 0, 0, 0);
            acc[2] = __builtin_amdgcn_mfma_f32_16x16x32_f16(Af[2][kt], Bfr[kt], acc[2], 0, 0, 0);
            acc[3] = __builtin_amdgcn_mfma_f32_16x16x32_f16(Af[3][kt], Bfr[kt], acc[3], 0, 0, 0);
        }
        const int n = ct * 16 + i;
        const float bias = bb[n] + ((n < 2 * HID) ? bb[GATE + n] : 0.0f);
#pragma unroll
        for (int rt = 0; rt < 4; ++rt)
#pragma unroll
            for (int r = 0; r < 4; ++r)
                xpout[(size_t)(mt * TC + rt * 16 + 4 * g + r) * GATE + n] =
                    (_Float16)(acc[rt][r] + bias);
    }
    __syncthreads();   // protect As before the next work item
}

// ---------------------------------------------------------------------------
// Layer-0 projection: batch chunk staged in LDS, W0 columns in registers
// (kills per-step scattered W0 re-loads). One item per batch element.
// ---------------------------------------------------------------------------
__device__ __forceinline__ void xp0_body(
    char* smem, const int* __restrict__ batch, const float* __restrict__ W0,
    const float* __restrict__ bb, _Float16* __restrict__ xpout, int t0, int b)
{
    int* bl = (int*)smem;   // [TC][FEAT] = 4KB
    const int T = threadIdx.x;
    for (int idx = T; idx < TC * FEAT; idx += NT)
        bl[idx] = batch[((size_t)b * SEQ + t0 + (idx >> 4)) * FEAT + (idx & 15)];
    __syncthreads();

    const int cc0 = T;            // 0..511
    const int cc1 = T + NT;       // 512..1023, valid if < GATE (T < 256)
    const bool two = (cc1 < GATE);

    float w0a[FEAT], w0b[FEAT];
#pragma unroll
    for (int f = 0; f < FEAT; ++f) w0a[f] = W0[f * GATE + cc0];
    if (two) {
#pragma unroll
        for (int f = 0; f < FEAT; ++f) w0b[f] = W0[f * GATE + cc1];
    }
    const float ba = bb[cc0] + ((cc0 < 2 * HID) ? bb[GATE + cc0] : 0.0f);
    const float bc = two ? (bb[cc1] + ((cc1 < 2 * HID) ? bb[GATE + cc1] : 0.0f)) : 0.0f;

    for (int tl = 0; tl < TC; ++tl) {
        float a0 = ba, a1 = bc;
#pragma unroll
        for (int f = 0; f < FEAT; ++f) {
            const float xf = (float)bl[tl * FEAT + f];   // LDS broadcast
            a0 += xf * w0a[f];
            if (two) a1 += xf * w0b[f];
        }
        _Float16* orow = xpout + ((size_t)b * TC + tl) * GATE;
        orow[cc0] = (_Float16)a0;
        if (two) orow[cc1] = (_Float16)a1;
    }
    __syncthreads();   // before smem reuse by the next item
}

// ---------------------------------------------------------------------------
// Fused pipeline kernel, EXACTLY 256 blocks (1 per CU).
// Launch d:
//   bid   0- 63 : gru layer0 chunk d     (batch = bid)
//   bid  64-127 : gru layer1 chunk d-2
//   bid 128-191 : gru layer2 chunk d-4
//   bid 192-255 : worker, 3 items each of 192:
//                 item 0-63    xp0 chunk d+1      (batch = item)
//                 item 64-127  gemm L1 chunk d-1  (M-tile = item-64)
//                 item 128-191 gemm L2 chunk d-3  (M-tile = item-128)
// ---------------------------------------------------------------------------
__global__ __launch_bounds__(NT, 1) void k_fused(Params P, int d)
{
    __shared__ __align__(16) char smem[64 * 264 * 2];   // 33792 B (max of roles)
    const int bid = blockIdx.x;

    if (bid < 64) {
        const int c = d;
        if (c >= 0 && c <= LASTC)
            gru_body(smem, (c & 1) ? P.xp0b : P.xp0a, P.Bf0, P.b0, P.batch,
                     (c & 1) ? P.y0b : P.y0a, nullptr, 0, nullptr, P.h0,
                     c * TC, bid);
    } else if (bid < 128) {
        const int c = d - 2;
        if (c >= 0 && c <= LASTC)
            gru_body(smem, (c & 1) ? P.xp1b : P.xp1a, P.Bf1, P.b1, P.batch,
                     (c & 1) ? P.y1b : P.y1a, nullptr, 0, nullptr, P.h1,
                     c * TC, bid - 64);
    } else if (bid < 192) {
        const int c = d - 4;
        if (c >= 0 && c <= LASTC)
            gru_body(smem, (c & 1) ? P.xp2b : P.xp2a, P.Bf2, P.b2, P.batch,
                     nullptr, P.out, c * TC, (c == LASTC) ? P.hfin : nullptr,
                     P.h2, c * TC, bid - 128);
    } else {
        for (int item = bid - 192; item < NITEM; item += NWRK) {
            if (item < 64) {
                const int c = d + 1;
                if (c >= 0 && c <= LASTC)
                    xp0_body(smem, P.batch, P.W0, P.b0,
                             (c & 1) ? P.xp0b : P.xp0a, c * TC, item);
            } else if (item < 128) {
                const int c = d - 1;
                if (c >= 0 && c <= LASTC)
                    gemm_mfma_body(smem, (c & 1) ? P.y0b : P.y0a, P.Wp1, P.b1,
                                   (c & 1) ? P.xp1b : P.xp1a, item - 64);
            } else {
                const int c = d - 3;
                if (c >= 0 && c <= LASTC)
                    gemm_mfma_body(smem, (c & 1) ? P.y1b : P.y1a, P.Wp2, P.b2,
                                   (c & 1) ? P.xp2b : P.xp2a, item - 128);
            }
        }
    }
}

// ---------------------------------------------------------------------------
extern "C" void kernel_launch(void* const* d_in, const int* in_sizes, int n_in,
                              void* d_out, int out_size, void* d_ws, size_t ws_size,
                              hipStream_t stream)
{
    const int*   batch = (const int*)d_in[0];
    const float* W0 = (const float*)d_in[1];
    const float* U0 = (const float*)d_in[2];
    const float* b0 = (const float*)d_in[3];
    const float* W1 = (const float*)d_in[4];
    const float* U1 = (const float*)d_in[5];
    const float* b1 = (const float*)d_in[6];
    const float* W2 = (const float*)d_in[7];
    const float* U2 = (const float*)d_in[8];
    const float* b2 = (const float*)d_in[9];

    float* out  = (float*)d_out;
    float* hfin = out + (size_t)BATCH * SEQ * HID;

    const size_t XPB = (size_t)BATCH * TC * GATE * 2;   // f16 xp chunk bytes
    const size_t YB  = (size_t)BATCH * TC * HID * 2;    // f16 y chunk bytes
    const size_t HB  = (size_t)BATCH * HID * 4;
    const size_t BFB = (size_t)48 * 8 * 64 * 4 * 4;     // packed-frag bytes

    char* p = (char*)d_ws;
    auto alloc = [&](size_t bytes) { char* q = p; p += (bytes + 255) & ~(size_t)255; return q; };
    _Float16* xp0a = (_Float16*)alloc(XPB);
    _Float16* xp0b = (_Float16*)alloc(XPB);
    _Float16* xp1a = (_Float16*)alloc(XPB);
    _Float16* xp1b = (_Float16*)alloc(XPB);
    _Float16* xp2a = (_Float16*)alloc(XPB);
    _Float16* xp2b = (_Float16*)alloc(XPB);
    _Float16* y0a  = (_Float16*)alloc(YB);
    _Float16* y0b  = (_Float16*)alloc(YB);
    _Float16* y1a  = (_Float16*)alloc(YB);
    _Float16* y1b  = (_Float16*)alloc(YB);
    float* h0  = (float*)alloc(HB);
    float* h1  = (float*)alloc(HB);
    float* h2  = (float*)alloc(HB);
    float* Bf0 = (float*)alloc(BFB);
    float* Bf1 = (float*)alloc(BFB);
    float* Bf2 = (float*)alloc(BFB);
    float* Wp1 = (float*)alloc(BFB);
    float* Wp2 = (float*)alloc(BFB);

    dim3 gpack(48 * 8 * 64 / 256), bpack(256);
    k_packB<<<gpack, bpack, 0, stream>>>(U0, Bf0);
    k_packB<<<gpack, bpack, 0, stream>>>(U1, Bf1);
    k_packB<<<gpack, bpack, 0, stream>>>(U2, Bf2);
    k_packB<<<gpack, bpack, 0, stream>>>(W1, Wp1);
    k_packB<<<gpack, bpack, 0, stream>>>(W2, Wp2);

    Params P;
    P.batch = batch;
    P.W0 = W0; P.b0 = b0; P.b1 = b1; P.b2 = b2;
    P.Bf0 = Bf0; P.Bf1 = Bf1; P.Bf2 = Bf2;
    P.Wp1 = Wp1; P.Wp2 = Wp2;
    P.xp0a = xp0a; P.xp0b = xp0b; P.xp1a = xp1a; P.xp1b = xp1b;
    P.xp2a = xp2a; P.xp2b = xp2b;
    P.y0a = y0a; P.y0b = y0b; P.y1a = y1a; P.y1b = y1b;
    P.h0 = h0; P.h1 = h1; P.h2 = h2;
    P.out = out; P.hfin = hfin;

    for (int d = -1; d <= LASTC + 4; ++d)
        k_fused<<<dim3(256), dim3(NT), 0, stream>>>(P, d);
}